// Round 8
// baseline (428.893 us; speedup 1.0000x reference)
//
#include <hip/hip_runtime.h>
#include <hip/hip_bf16.h>

// GCN (2-layer, PyG-style symmetric norm + self loops) + edge MLP.
//  - CSR by dst (hist -> 3-level scan -> fill). No fp32 atomics.
//  - gcn_conv: t' = (h@W) * dinv[row] (producer-side scale), then per-node:
//      out[v] = relu(dinv[v]*( t'[v] + sum_{(s,v)} t'[s] ) + b)
//  - Edge MLP: ef@Wm1 = A[src]+B[dst], A/B precomputed per node.
// R2: 3-level scan replaces single-block scan (was 111us @ 0.14% occ).
// R3: k_edge_mlp in CSR(dst) order -> B[d] wave-broadcast; 107->63.6us.
// R4: per-node GEMMs fused into k_agg epilogue.
// R5: coop batch index load + readlane broadcast (82->72us).
// R6: dinv folded into producer rows; 8 gathers in flight; no LDS/barrier.
// R7: epilogue weights made WAVE-RESIDENT (64/128 VGPRs of Wepi[.][lane]) +
//     grid-stride node loop: kills the 32KB/node Wepi re-stream (~23TB/s of
//     L1 traffic, the real co-limiter with VALU) and amortizes it over ~16
//     nodes/wave. Epilogue = readlane + register FMA only.

#define HDIM 64
#define CDIM 16

static inline int ceil_div(int a, int b){ return (a+b-1)/b; }

__device__ inline float readlane_f(float v, int l){
  return __uint_as_float(__builtin_amdgcn_readlane(__float_as_uint(v), l));
}

__global__ void k_zero_i32(int* p, int n){
  int i = blockIdx.x*blockDim.x + threadIdx.x;
  if(i<n) p[i]=0;
}

__global__ void k_hist(const int* __restrict__ dst, int* __restrict__ cnt, int E){
  int e = blockIdx.x*blockDim.x + threadIdx.x;
  if(e<E) atomicAdd(&cnt[dst[e]], 1);
}

// Level 1: per-block (256 nodes) sum of cnt -> bsum[block]
__global__ __launch_bounds__(256) void k_blocksum(const int* __restrict__ cnt,
                                                  int* __restrict__ bsum, int N){
  __shared__ int part[4];
  int i = blockIdx.x*256 + threadIdx.x;
  int v = (i<N) ? cnt[i] : 0;
  #pragma unroll
  for(int off=32; off>0; off>>=1) v += __shfl_down(v, off, 64);
  if((threadIdx.x & 63)==0) part[threadIdx.x>>6] = v;
  __syncthreads();
  if(threadIdx.x==0) bsum[blockIdx.x] = part[0]+part[1]+part[2]+part[3];
}

// Level 2: one block scans the per-block sums (nb <= 1024) -> exclusive prefix.
__global__ __launch_bounds__(1024) void k_scan_bsums(int* __restrict__ bsum, int nb){
  __shared__ int tmp[1024];
  int tid = threadIdx.x;
  int v = (tid<nb) ? bsum[tid] : 0;
  tmp[tid] = v; __syncthreads();
  for(int off=1; off<1024; off<<=1){
    int add = (tid>=off) ? tmp[tid-off] : 0;
    __syncthreads();
    tmp[tid] += add;
    __syncthreads();
  }
  if(tid<nb) bsum[tid] = tmp[tid] - v;   // exclusive
}

// Level 3: in-block exclusive scan of cnt + block offset -> row_start/cursor.
// Also computes dinv (needs only cnt).
__global__ __launch_bounds__(256) void k_write_prefix(const int* __restrict__ cnt,
                                                      const int* __restrict__ bsum,
                                                      int* __restrict__ row_start,
                                                      int* __restrict__ cursor,
                                                      float* __restrict__ dinv, int N){
  __shared__ int tmp[256];
  int tid = threadIdx.x;
  int i = blockIdx.x*256 + tid;
  int v = (i<N) ? cnt[i] : 0;
  tmp[tid] = v; __syncthreads();
  for(int off=1; off<256; off<<=1){
    int add = (tid>=off) ? tmp[tid-off] : 0;
    __syncthreads();
    tmp[tid] += add;
    __syncthreads();
  }
  if(i<N){
    int ex = bsum[blockIdx.x] + tmp[tid] - v;
    row_start[i] = ex;
    cursor[i]    = ex;
    dinv[i]      = 1.0f / sqrtf(1.0f + (float)v);  // deg >= 1 via self-loop
  }
}

__global__ void k_fill(const int* __restrict__ src, const int* __restrict__ dst,
                       int* __restrict__ cursor,
                       int* __restrict__ csr_src, int* __restrict__ csr_dst,
                       int* __restrict__ csr_eid, int E){
  int e = blockIdx.x*blockDim.x + threadIdx.x;
  if(e>=E) return;
  int s = src[e], d = dst[e];
  int pos = atomicAdd(&cursor[d], 1);
  csr_src[pos] = s;
  csr_dst[pos] = d;
  csr_eid[pos] = e;
}

// out[n][c] = (sum_k in[n][k] * W[k][c]) * dscale[n]; one block = 4 nodes,
// input rows staged in LDS, W coalesced + L1-resident.
template<int K, int COLS>
__global__ __launch_bounds__(256) void k_gemm(const float* __restrict__ in,
                                              const float* __restrict__ W,
                                              const float* __restrict__ dscale,
                                              float* __restrict__ out, int N){
  const int NODES = 256/COLS;
  __shared__ float srow[NODES*K];
  int n0 = blockIdx.x*NODES;
  for(int i=threadIdx.x; i<NODES*K; i+=256){
    int g = n0*K + i;
    srow[i] = (g < N*K) ? in[g] : 0.f;
  }
  __syncthreads();
  int c = threadIdx.x % COLS;
  int y = threadIdx.x / COLS;
  int n = n0+y;
  if(n>=N) return;
  float acc=0.f;
  #pragma unroll
  for(int k=0;k<K;k++) acc += srow[y*K+k]*W[k*COLS+c];
  out[n*COLS+c]=acc*dscale[n];
}

// Fused: gather-aggregate over pre-scaled t' -> r = relu(acc*dv + b) ->
// per-node GEMM vs WAVE-RESIDENT weights wr[g][k] = Wepi[(g*64+k)*64+lane]
// (loaded once per wave; epilogue is readlane + register FMA, no memory).
// Grid-stride over nodes (one node per wave per iteration) amortizes the
// weight prologue. MINW caps VGPRs via launch_bounds (G=1:4 waves/EU cap128,
// G=2:2 waves/EU cap256).
template<int GROUPS, bool SCALE_OUT, int MINW>
__global__ __launch_bounds__(256, MINW)
void k_agg_fused(const float* __restrict__ t,
                 const int* __restrict__ csr_src,
                 const int* __restrict__ row_start,
                 const int* __restrict__ cnt,
                 const float* __restrict__ dinv,
                 const float* __restrict__ bias,
                 const float* __restrict__ Wepi,
                 float* __restrict__ outbuf, int N, int total_waves){
  int lane = threadIdx.x & 63;
  int wid  = (blockIdx.x*blockDim.x + threadIdx.x) >> 6;   // global wave id

  // --- wave-resident weights + bias (VGPR prologue) ---
  float wr[GROUPS][HDIM];
  #pragma unroll
  for(int g=0; g<GROUPS; g++){
    #pragma unroll
    for(int k=0; k<HDIM; k++)
      wr[g][k] = Wepi[(size_t)(g*HDIM + k)*HDIM + lane];
  }
  float bias_l = bias[lane];

  for(int v = wid; v < N; v += total_waves){
    float dv = dinv[v];
    float a0 = t[(size_t)v*HDIM + lane];   // self term (t' already has dinv[v])
    float a1=0.f,a2=0.f,a3=0.f,a4=0.f,a5=0.f,a6=0.f,a7=0.f;
    int j0  = row_start[v];
    int deg = cnt[v];

    for(int b=0; b<deg; b+=64){
      int m = deg - b; if(m>64) m=64;
      int idxv = 0;
      if(lane < m) idxv = csr_src[j0 + b + lane];  // one coalesced load per batch
      int k=0;
      for(; k+7<m; k+=8){
        int s0 = __builtin_amdgcn_readlane(idxv, k);
        int s1 = __builtin_amdgcn_readlane(idxv, k+1);
        int s2 = __builtin_amdgcn_readlane(idxv, k+2);
        int s3 = __builtin_amdgcn_readlane(idxv, k+3);
        int s4 = __builtin_amdgcn_readlane(idxv, k+4);
        int s5 = __builtin_amdgcn_readlane(idxv, k+5);
        int s6 = __builtin_amdgcn_readlane(idxv, k+6);
        int s7 = __builtin_amdgcn_readlane(idxv, k+7);
        a0 += t[(size_t)s0*HDIM+lane];
        a1 += t[(size_t)s1*HDIM+lane];
        a2 += t[(size_t)s2*HDIM+lane];
        a3 += t[(size_t)s3*HDIM+lane];
        a4 += t[(size_t)s4*HDIM+lane];
        a5 += t[(size_t)s5*HDIM+lane];
        a6 += t[(size_t)s6*HDIM+lane];
        a7 += t[(size_t)s7*HDIM+lane];
      }
      for(; k<m; k++){
        int s = __builtin_amdgcn_readlane(idxv, k);
        a0 += t[(size_t)s*HDIM+lane];
      }
    }
    float acc = ((a0+a1)+(a2+a3)) + ((a4+a5)+(a6+a7));
    float r = acc*dv + bias_l;
    r = r>0.f ? r : 0.f;                 // h-row value for feature `lane`

    float s_out[GROUPS];
    #pragma unroll
    for(int g=0; g<GROUPS; g++) s_out[g] = 0.f;
    #pragma unroll
    for(int k=0; k<HDIM; k++){
      float hv = readlane_f(r, k);       // wave-broadcast of feature k
      #pragma unroll
      for(int g=0; g<GROUPS; g++)
        s_out[g] += hv * wr[g][k];       // pure register FMA
    }
    #pragma unroll
    for(int g=0; g<GROUPS; g++){
      float o = SCALE_OUT ? s_out[g]*dv : s_out[g];
      outbuf[(size_t)v*(GROUPS*HDIM) + g*HDIM + lane] = o;
    }
  }
}

// Edge MLP in CSR(dst) order: thread j -> (s, d, eid). Consecutive threads share
// d -> B[d] reads broadcast/stream. A[s] random: 16 float4 loads in flight.
__global__ __launch_bounds__(256) void k_edge_mlp(const int* __restrict__ csr_src,
                                                  const int* __restrict__ csr_dst,
                                                  const int* __restrict__ csr_eid,
                                                  const float* __restrict__ AB,
                                                  const float* __restrict__ bm1,
                                                  const float* __restrict__ Wm2,
                                                  const float* __restrict__ bm2,
                                                  float* __restrict__ out, int E){
  int j = blockIdx.x*blockDim.x + threadIdx.x;
  if(j>=E) return;
  int s = csr_src[j], d = csr_dst[j], eid = csr_eid[j];
  const float4* Af = (const float4*)(AB + (size_t)s*128);
  const float4* Bf = (const float4*)(AB + (size_t)d*128 + 64);
  const float4* bm1f = (const float4*)bm1;
  const float4* bm2f = (const float4*)bm2;

  float4 a[16];
  #pragma unroll
  for(int k0=0;k0<16;k0++) a[k0] = Af[k0];   // random-side gather, 16 in flight

  float acc[CDIM];
  {
    float4 c0 = bm2f[0], c1 = bm2f[1], c2 = bm2f[2], c3 = bm2f[3];
    acc[0]=c0.x; acc[1]=c0.y; acc[2]=c0.z; acc[3]=c0.w;
    acc[4]=c1.x; acc[5]=c1.y; acc[6]=c1.z; acc[7]=c1.w;
    acc[8]=c2.x; acc[9]=c2.y; acc[10]=c2.z; acc[11]=c2.w;
    acc[12]=c3.x; acc[13]=c3.y; acc[14]=c3.z; acc[15]=c3.w;
  }
  #pragma unroll
  for(int k0=0;k0<16;k0++){
    float4 b  = Bf[k0];     // same d across wave -> broadcast / L1-hit
    float4 bb = bm1f[k0];   // wave-uniform -> s_load
    float z0 = a[k0].x+b.x+bb.x; z0 = z0>0.f? z0:0.f;
    float z1 = a[k0].y+b.y+bb.y; z1 = z1>0.f? z1:0.f;
    float z2 = a[k0].z+b.z+bb.z; z2 = z2>0.f? z2:0.f;
    float z3 = a[k0].w+b.w+bb.w; z3 = z3>0.f? z3:0.f;
    #pragma unroll
    for(int c=0;c<CDIM;c++){
      acc[c] += z0 * Wm2[(k0*4+0)*CDIM + c];
      acc[c] += z1 * Wm2[(k0*4+1)*CDIM + c];
      acc[c] += z2 * Wm2[(k0*4+2)*CDIM + c];
      acc[c] += z3 * Wm2[(k0*4+3)*CDIM + c];
    }
  }
  float4* o = (float4*)(out + (size_t)eid*CDIM);
  o[0] = make_float4(acc[0],acc[1],acc[2],acc[3]);
  o[1] = make_float4(acc[4],acc[5],acc[6],acc[7]);
  o[2] = make_float4(acc[8],acc[9],acc[10],acc[11]);
  o[3] = make_float4(acc[12],acc[13],acc[14],acc[15]);
}

extern "C" void kernel_launch(void* const* d_in, const int* in_sizes, int n_in,
                              void* d_out, int out_size, void* d_ws, size_t ws_size,
                              hipStream_t stream) {
  const float* x   = (const float*)d_in[0];
  const int*   ei  = (const int*)  d_in[1];
  const float* W1  = (const float*)d_in[2];
  const float* b1  = (const float*)d_in[3];
  const float* W2  = (const float*)d_in[4];
  const float* b2  = (const float*)d_in[5];
  const float* Wm1 = (const float*)d_in[6];
  const float* bm1 = (const float*)d_in[7];
  const float* Wm2 = (const float*)d_in[8];
  const float* bm2 = (const float*)d_in[9];
  float* out = (float*)d_out;

  const int N = in_sizes[0]/128;
  const int E = in_sizes[1]/2;
  const int* src = ei;
  const int* dst = ei + E;

  const int NB = ceil_div(N,256);

  // ws layout (256B-aligned). t1 (N*64) aliases AB's low half: t1 is dead
  // (last read by aggF<1>) before aggF<2> writes AB.
  char* ws = (char*)d_ws;
  size_t off = 0;
  auto alloc = [&](size_t bytes)->char*{
    char* p = ws + off; off += (bytes + 255) & ~(size_t)255; return p;
  };
  int*   cnt       = (int*)  alloc((size_t)N*4);
  int*   row_start = (int*)  alloc((size_t)N*4);
  int*   cursor    = (int*)  alloc((size_t)N*4);
  float* dinv      = (float*)alloc((size_t)N*4);
  int*   bsum      = (int*)  alloc((size_t)NB*4);
  int*   csr_src   = (int*)  alloc((size_t)E*4);
  int*   csr_dst   = (int*)  alloc((size_t)E*4);
  int*   csr_eid   = (int*)  alloc((size_t)E*4);
  float* AB        = (float*)alloc((size_t)N*128*4);
  float* t1        = AB;                               // alias: low 12.8MB of AB
  float* t2        = (float*)alloc((size_t)N*64*4);

  // --- CSR build ---
  k_zero_i32    <<<ceil_div(N,256),256,0,stream>>>(cnt, N);
  k_hist        <<<ceil_div(E,256),256,0,stream>>>(dst, cnt, E);
  k_blocksum    <<<NB,256,0,stream>>>(cnt, bsum, N);
  k_scan_bsums  <<<1,1024,0,stream>>>(bsum, NB);
  k_write_prefix<<<NB,256,0,stream>>>(cnt, bsum, row_start, cursor, dinv, N);
  k_fill        <<<ceil_div(E,256),256,0,stream>>>(src, dst, cursor,
                                                   csr_src, csr_dst, csr_eid, E);

  // --- layer 1: t1' = (x@W1)*dinv ---
  k_gemm<128,64><<<ceil_div(N,4),256,0,stream>>>(x, W1, dinv, t1, N);

  // --- agg1 + fused (h1@W2), output pre-scaled: t2' ---
  {
    const int blocks = 1024;                    // ~4 blocks/CU, 16 waves/CU
    const int tw = blocks*4;                    // waves in grid
    k_agg_fused<1,true,4><<<blocks,256,0,stream>>>(t1, csr_src, row_start, cnt,
                                                   dinv, b1, W2, t2, N, tw);
  }
  // --- agg2 + fused (h2@Wm1): AB (unscaled) ---
  {
    const int blocks = 512;                     // ~2 blocks/CU, 8 waves/CU
    const int tw = blocks*4;
    k_agg_fused<2,false,2><<<blocks,256,0,stream>>>(t2, csr_src, row_start, cnt,
                                                    dinv, b2, Wm1, AB, N, tw);
  }
  // --- edge MLP ---
  k_edge_mlp<<<ceil_div(E,256),256,0,stream>>>(csr_src, csr_dst, csr_eid, AB,
                                               bm1, Wm2, bm2, out, E);
}

// Round 9
// 409.881 us; speedup vs baseline: 1.0464x; 1.0464x over previous
//
#include <hip/hip_runtime.h>
#include <hip/hip_bf16.h>

// GCN (2-layer, PyG-style symmetric norm + self loops) + edge MLP.
//  - CSR by dst (hist -> 3-level scan -> fill). No fp32 atomics.
//  - gcn_conv: t' = (h@W) * dinv[row] (producer-side scale), then per-node:
//      out[v] = relu(dinv[v]*( t'[v] + sum_{(s,v)} t'[s] ) + b)
//  - Edge MLP: ef@Wm1 = A[src]+B[dst], A/B precomputed per node.
// R2: 3-level scan replaces single-block scan (was 111us @ 0.14% occ).
// R3: k_edge_mlp in CSR(dst) order -> B[d] wave-broadcast; 107->63.6us.
// R4: per-node GEMMs fused into k_agg epilogue.
// R5: coop batch index load + readlane broadcast (82->72us).
// R6: dinv folded into producer rows; 8 gathers in flight; no LDS/barrier.
// R7: REGRESSED (wave-resident weights + small grid-stride grid starved TLP:
//     occupancy 70->20%, 69.5->89.8us). Reverted.
// R8: R6 structure restored; gather pipeline deepened to 16 accumulators /
//     16 outstanding loads per wave (vmcnt drain was emptying the pipe every
//     8 edges -> one full L2/L3 latency stall per 8 edges).

#define HDIM 64
#define CDIM 16

static inline int ceil_div(int a, int b){ return (a+b-1)/b; }

__device__ inline float readlane_f(float v, int l){
  return __uint_as_float(__builtin_amdgcn_readlane(__float_as_uint(v), l));
}

__global__ void k_zero_i32(int* p, int n){
  int i = blockIdx.x*blockDim.x + threadIdx.x;
  if(i<n) p[i]=0;
}

__global__ void k_hist(const int* __restrict__ dst, int* __restrict__ cnt, int E){
  int e = blockIdx.x*blockDim.x + threadIdx.x;
  if(e<E) atomicAdd(&cnt[dst[e]], 1);
}

// Level 1: per-block (256 nodes) sum of cnt -> bsum[block]
__global__ __launch_bounds__(256) void k_blocksum(const int* __restrict__ cnt,
                                                  int* __restrict__ bsum, int N){
  __shared__ int part[4];
  int i = blockIdx.x*256 + threadIdx.x;
  int v = (i<N) ? cnt[i] : 0;
  #pragma unroll
  for(int off=32; off>0; off>>=1) v += __shfl_down(v, off, 64);
  if((threadIdx.x & 63)==0) part[threadIdx.x>>6] = v;
  __syncthreads();
  if(threadIdx.x==0) bsum[blockIdx.x] = part[0]+part[1]+part[2]+part[3];
}

// Level 2: one block scans the per-block sums (nb <= 1024) -> exclusive prefix.
__global__ __launch_bounds__(1024) void k_scan_bsums(int* __restrict__ bsum, int nb){
  __shared__ int tmp[1024];
  int tid = threadIdx.x;
  int v = (tid<nb) ? bsum[tid] : 0;
  tmp[tid] = v; __syncthreads();
  for(int off=1; off<1024; off<<=1){
    int add = (tid>=off) ? tmp[tid-off] : 0;
    __syncthreads();
    tmp[tid] += add;
    __syncthreads();
  }
  if(tid<nb) bsum[tid] = tmp[tid] - v;   // exclusive
}

// Level 3: in-block exclusive scan of cnt + block offset -> row_start/cursor.
// Also computes dinv (needs only cnt).
__global__ __launch_bounds__(256) void k_write_prefix(const int* __restrict__ cnt,
                                                      const int* __restrict__ bsum,
                                                      int* __restrict__ row_start,
                                                      int* __restrict__ cursor,
                                                      float* __restrict__ dinv, int N){
  __shared__ int tmp[256];
  int tid = threadIdx.x;
  int i = blockIdx.x*256 + tid;
  int v = (i<N) ? cnt[i] : 0;
  tmp[tid] = v; __syncthreads();
  for(int off=1; off<256; off<<=1){
    int add = (tid>=off) ? tmp[tid-off] : 0;
    __syncthreads();
    tmp[tid] += add;
    __syncthreads();
  }
  if(i<N){
    int ex = bsum[blockIdx.x] + tmp[tid] - v;
    row_start[i] = ex;
    cursor[i]    = ex;
    dinv[i]      = 1.0f / sqrtf(1.0f + (float)v);  // deg >= 1 via self-loop
  }
}

__global__ void k_fill(const int* __restrict__ src, const int* __restrict__ dst,
                       int* __restrict__ cursor,
                       int* __restrict__ csr_src, int* __restrict__ csr_dst,
                       int* __restrict__ csr_eid, int E){
  int e = blockIdx.x*blockDim.x + threadIdx.x;
  if(e>=E) return;
  int s = src[e], d = dst[e];
  int pos = atomicAdd(&cursor[d], 1);
  csr_src[pos] = s;
  csr_dst[pos] = d;
  csr_eid[pos] = e;
}

// out[n][c] = (sum_k in[n][k] * W[k][c]) * dscale[n]; one block = 4 nodes,
// input rows staged in LDS, W coalesced + L1-resident.
template<int K, int COLS>
__global__ __launch_bounds__(256) void k_gemm(const float* __restrict__ in,
                                              const float* __restrict__ W,
                                              const float* __restrict__ dscale,
                                              float* __restrict__ out, int N){
  const int NODES = 256/COLS;
  __shared__ float srow[NODES*K];
  int n0 = blockIdx.x*NODES;
  for(int i=threadIdx.x; i<NODES*K; i+=256){
    int g = n0*K + i;
    srow[i] = (g < N*K) ? in[g] : 0.f;
  }
  __syncthreads();
  int c = threadIdx.x % COLS;
  int y = threadIdx.x / COLS;
  int n = n0+y;
  if(n>=N) return;
  float acc=0.f;
  #pragma unroll
  for(int k=0;k<K;k++) acc += srow[y*K+k]*W[k*COLS+c];
  out[n*COLS+c]=acc*dscale[n];
}

// Fused: gather-aggregate over pre-scaled t' -> r = relu(acc*dv + b) ->
// per-node GEMM epilogue vs Wepi (GROUPS*64 x 64 row-major) via readlane
// broadcast (no LDS, no barrier). SCALE_OUT: store s_out*dv (produce next t').
// Gather: coop batch load of <=64 src indices (1 coalesced load), readlane
// broadcast, SIXTEEN independent 256B row gathers in flight (R8: the 8-deep
// pipe drained vmcnt->0 every 8 edges, paying one full L2/L3 latency per 8).
template<int GROUPS, bool SCALE_OUT>
__global__ __launch_bounds__(256) void k_agg_fused(const float* __restrict__ t,
                                                   const int* __restrict__ csr_src,
                                                   const int* __restrict__ row_start,
                                                   const int* __restrict__ cnt,
                                                   const float* __restrict__ dinv,
                                                   const float* __restrict__ bias,
                                                   const float* __restrict__ Wepi,
                                                   float* __restrict__ outbuf, int N){
  int lane = threadIdx.x & 63;
  int w    = threadIdx.x >> 6;
  int v    = blockIdx.x*4 + w;
  bool act = (v < N);
  int vv   = act ? v : 0;

  float dv = dinv[vv];
  float a0 = t[(size_t)vv*HDIM + lane];   // self term (t' already has dinv[v])
  float a1=0.f,a2=0.f,a3=0.f,a4=0.f,a5=0.f,a6=0.f,a7=0.f;
  float a8=0.f,a9=0.f,aA=0.f,aB=0.f,aC=0.f,aD=0.f,aE=0.f,aF=0.f;
  int j0  = act ? row_start[vv] : 0;
  int deg = act ? cnt[vv] : 0;

  for(int b=0; b<deg; b+=64){
    int m = deg - b; if(m>64) m=64;
    int idxv = 0;
    if(lane < m) idxv = csr_src[j0 + b + lane];  // one coalesced load per batch
    int k=0;
    for(; k+15<m; k+=16){
      int s0 = __builtin_amdgcn_readlane(idxv, k);
      int s1 = __builtin_amdgcn_readlane(idxv, k+1);
      int s2 = __builtin_amdgcn_readlane(idxv, k+2);
      int s3 = __builtin_amdgcn_readlane(idxv, k+3);
      int s4 = __builtin_amdgcn_readlane(idxv, k+4);
      int s5 = __builtin_amdgcn_readlane(idxv, k+5);
      int s6 = __builtin_amdgcn_readlane(idxv, k+6);
      int s7 = __builtin_amdgcn_readlane(idxv, k+7);
      int s8 = __builtin_amdgcn_readlane(idxv, k+8);
      int s9 = __builtin_amdgcn_readlane(idxv, k+9);
      int sA = __builtin_amdgcn_readlane(idxv, k+10);
      int sB = __builtin_amdgcn_readlane(idxv, k+11);
      int sC = __builtin_amdgcn_readlane(idxv, k+12);
      int sD = __builtin_amdgcn_readlane(idxv, k+13);
      int sE = __builtin_amdgcn_readlane(idxv, k+14);
      int sF = __builtin_amdgcn_readlane(idxv, k+15);
      float t0 = t[(size_t)s0*HDIM+lane];
      float t1 = t[(size_t)s1*HDIM+lane];
      float t2 = t[(size_t)s2*HDIM+lane];
      float t3 = t[(size_t)s3*HDIM+lane];
      float t4 = t[(size_t)s4*HDIM+lane];
      float t5 = t[(size_t)s5*HDIM+lane];
      float t6 = t[(size_t)s6*HDIM+lane];
      float t7 = t[(size_t)s7*HDIM+lane];
      float t8 = t[(size_t)s8*HDIM+lane];
      float t9 = t[(size_t)s9*HDIM+lane];
      float tA = t[(size_t)sA*HDIM+lane];
      float tB = t[(size_t)sB*HDIM+lane];
      float tC = t[(size_t)sC*HDIM+lane];
      float tD = t[(size_t)sD*HDIM+lane];
      float tE = t[(size_t)sE*HDIM+lane];
      float tF = t[(size_t)sF*HDIM+lane];
      a0+=t0; a1+=t1; a2+=t2; a3+=t3; a4+=t4; a5+=t5; a6+=t6; a7+=t7;
      a8+=t8; a9+=t9; aA+=tA; aB+=tB; aC+=tC; aD+=tD; aE+=tE; aF+=tF;
    }
    for(; k+7<m; k+=8){
      int s0 = __builtin_amdgcn_readlane(idxv, k);
      int s1 = __builtin_amdgcn_readlane(idxv, k+1);
      int s2 = __builtin_amdgcn_readlane(idxv, k+2);
      int s3 = __builtin_amdgcn_readlane(idxv, k+3);
      int s4 = __builtin_amdgcn_readlane(idxv, k+4);
      int s5 = __builtin_amdgcn_readlane(idxv, k+5);
      int s6 = __builtin_amdgcn_readlane(idxv, k+6);
      int s7 = __builtin_amdgcn_readlane(idxv, k+7);
      float t0 = t[(size_t)s0*HDIM+lane];
      float t1 = t[(size_t)s1*HDIM+lane];
      float t2 = t[(size_t)s2*HDIM+lane];
      float t3 = t[(size_t)s3*HDIM+lane];
      float t4 = t[(size_t)s4*HDIM+lane];
      float t5 = t[(size_t)s5*HDIM+lane];
      float t6 = t[(size_t)s6*HDIM+lane];
      float t7 = t[(size_t)s7*HDIM+lane];
      a0+=t0; a1+=t1; a2+=t2; a3+=t3; a4+=t4; a5+=t5; a6+=t6; a7+=t7;
    }
    for(; k<m; k++){
      int s = __builtin_amdgcn_readlane(idxv, k);
      a0 += t[(size_t)s*HDIM+lane];
    }
  }
  float acc = (((a0+a1)+(a2+a3)) + ((a4+a5)+(a6+a7)))
            + (((a8+a9)+(aA+aB)) + ((aC+aD)+(aE+aF)));
  float r = acc*dv + bias[lane];
  r = r>0.f ? r : 0.f;                 // h-row value for feature `lane`

  float s_out[GROUPS];
  #pragma unroll
  for(int g=0; g<GROUPS; g++) s_out[g] = 0.f;
  #pragma unroll
  for(int k=0; k<HDIM; k++){
    float hv = readlane_f(r, k);       // wave-broadcast of feature k
    #pragma unroll
    for(int g=0; g<GROUPS; g++)
      s_out[g] += hv * Wepi[(size_t)(g*HDIM + k)*HDIM + lane];  // coalesced, L1-hit
  }
  if(act){
    #pragma unroll
    for(int g=0; g<GROUPS; g++){
      float o = SCALE_OUT ? s_out[g]*dv : s_out[g];
      outbuf[(size_t)v*(GROUPS*HDIM) + g*HDIM + lane] = o;
    }
  }
}

// Edge MLP in CSR(dst) order: thread j -> (s, d, eid). Consecutive threads share
// d -> B[d] reads broadcast/stream. A[s] random: 16 float4 loads in flight.
__global__ __launch_bounds__(256) void k_edge_mlp(const int* __restrict__ csr_src,
                                                  const int* __restrict__ csr_dst,
                                                  const int* __restrict__ csr_eid,
                                                  const float* __restrict__ AB,
                                                  const float* __restrict__ bm1,
                                                  const float* __restrict__ Wm2,
                                                  const float* __restrict__ bm2,
                                                  float* __restrict__ out, int E){
  int j = blockIdx.x*blockDim.x + threadIdx.x;
  if(j>=E) return;
  int s = csr_src[j], d = csr_dst[j], eid = csr_eid[j];
  const float4* Af = (const float4*)(AB + (size_t)s*128);
  const float4* Bf = (const float4*)(AB + (size_t)d*128 + 64);
  const float4* bm1f = (const float4*)bm1;
  const float4* bm2f = (const float4*)bm2;

  float4 a[16];
  #pragma unroll
  for(int k0=0;k0<16;k0++) a[k0] = Af[k0];   // random-side gather, 16 in flight

  float acc[CDIM];
  {
    float4 c0 = bm2f[0], c1 = bm2f[1], c2 = bm2f[2], c3 = bm2f[3];
    acc[0]=c0.x; acc[1]=c0.y; acc[2]=c0.z; acc[3]=c0.w;
    acc[4]=c1.x; acc[5]=c1.y; acc[6]=c1.z; acc[7]=c1.w;
    acc[8]=c2.x; acc[9]=c2.y; acc[10]=c2.z; acc[11]=c2.w;
    acc[12]=c3.x; acc[13]=c3.y; acc[14]=c3.z; acc[15]=c3.w;
  }
  #pragma unroll
  for(int k0=0;k0<16;k0++){
    float4 b  = Bf[k0];     // same d across wave -> broadcast / L1-hit
    float4 bb = bm1f[k0];   // wave-uniform -> s_load
    float z0 = a[k0].x+b.x+bb.x; z0 = z0>0.f? z0:0.f;
    float z1 = a[k0].y+b.y+bb.y; z1 = z1>0.f? z1:0.f;
    float z2 = a[k0].z+b.z+bb.z; z2 = z2>0.f? z2:0.f;
    float z3 = a[k0].w+b.w+bb.w; z3 = z3>0.f? z3:0.f;
    #pragma unroll
    for(int c=0;c<CDIM;c++){
      acc[c] += z0 * Wm2[(k0*4+0)*CDIM + c];
      acc[c] += z1 * Wm2[(k0*4+1)*CDIM + c];
      acc[c] += z2 * Wm2[(k0*4+2)*CDIM + c];
      acc[c] += z3 * Wm2[(k0*4+3)*CDIM + c];
    }
  }
  float4* o = (float4*)(out + (size_t)eid*CDIM);
  o[0] = make_float4(acc[0],acc[1],acc[2],acc[3]);
  o[1] = make_float4(acc[4],acc[5],acc[6],acc[7]);
  o[2] = make_float4(acc[8],acc[9],acc[10],acc[11]);
  o[3] = make_float4(acc[12],acc[13],acc[14],acc[15]);
}

extern "C" void kernel_launch(void* const* d_in, const int* in_sizes, int n_in,
                              void* d_out, int out_size, void* d_ws, size_t ws_size,
                              hipStream_t stream) {
  const float* x   = (const float*)d_in[0];
  const int*   ei  = (const int*)  d_in[1];
  const float* W1  = (const float*)d_in[2];
  const float* b1  = (const float*)d_in[3];
  const float* W2  = (const float*)d_in[4];
  const float* b2  = (const float*)d_in[5];
  const float* Wm1 = (const float*)d_in[6];
  const float* bm1 = (const float*)d_in[7];
  const float* Wm2 = (const float*)d_in[8];
  const float* bm2 = (const float*)d_in[9];
  float* out = (float*)d_out;

  const int N = in_sizes[0]/128;
  const int E = in_sizes[1]/2;
  const int* src = ei;
  const int* dst = ei + E;

  const int NB = ceil_div(N,256);

  // ws layout (256B-aligned). t1 (N*64) aliases AB's low half: t1 is dead
  // (last read by aggF<1>) before aggF<2> writes AB.
  char* ws = (char*)d_ws;
  size_t off = 0;
  auto alloc = [&](size_t bytes)->char*{
    char* p = ws + off; off += (bytes + 255) & ~(size_t)255; return p;
  };
  int*   cnt       = (int*)  alloc((size_t)N*4);
  int*   row_start = (int*)  alloc((size_t)N*4);
  int*   cursor    = (int*)  alloc((size_t)N*4);
  float* dinv      = (float*)alloc((size_t)N*4);
  int*   bsum      = (int*)  alloc((size_t)NB*4);
  int*   csr_src   = (int*)  alloc((size_t)E*4);
  int*   csr_dst   = (int*)  alloc((size_t)E*4);
  int*   csr_eid   = (int*)  alloc((size_t)E*4);
  float* AB        = (float*)alloc((size_t)N*128*4);
  float* t1        = AB;                               // alias: low 12.8MB of AB
  float* t2        = (float*)alloc((size_t)N*64*4);

  // --- CSR build ---
  k_zero_i32    <<<ceil_div(N,256),256,0,stream>>>(cnt, N);
  k_hist        <<<ceil_div(E,256),256,0,stream>>>(dst, cnt, E);
  k_blocksum    <<<NB,256,0,stream>>>(cnt, bsum, N);
  k_scan_bsums  <<<1,1024,0,stream>>>(bsum, NB);
  k_write_prefix<<<NB,256,0,stream>>>(cnt, bsum, row_start, cursor, dinv, N);
  k_fill        <<<ceil_div(E,256),256,0,stream>>>(src, dst, cursor,
                                                   csr_src, csr_dst, csr_eid, E);

  // --- layer 1: t1' = (x@W1)*dinv ---
  k_gemm<128,64><<<ceil_div(N,4),256,0,stream>>>(x, W1, dinv, t1, N);
  // --- agg1 + fused (h1@W2), output pre-scaled: t2' ---
  k_agg_fused<1,true ><<<ceil_div(N,4),256,0,stream>>>(t1, csr_src, row_start, cnt,
                                                       dinv, b1, W2, t2, N);
  // --- agg2 + fused (h2@Wm1): AB (unscaled) ---
  k_agg_fused<2,false><<<ceil_div(N,4),256,0,stream>>>(t2, csr_src, row_start, cnt,
                                                       dinv, b2, Wm1, AB, N);
  // --- edge MLP ---
  k_edge_mlp<<<ceil_div(E,256),256,0,stream>>>(csr_src, csr_dst, csr_eid, AB,
                                               bm1, Wm2, bm2, out, E);
}